// Round 6
// baseline (370.394 us; speedup 1.0000x reference)
//
#include <hip/hip_runtime.h>
#include <hip/hip_bf16.h>

#define NPTS 65536
#define NU_F 0.0031830988618379067f

typedef __attribute__((ext_vector_type(8)))  short short8v;   // 8 bf16 (4 VGPRs)
typedef __attribute__((ext_vector_type(16))) float f32x16;    // 32x32 MFMA C/D

__device__ __forceinline__ ushort f2bf(float f) {
    union { __hip_bfloat16 b; ushort u; } cv;
    cv.b = __float2bfloat16(f);          // HW RNE convert
    return cv.u;
}
__device__ __forceinline__ float bf2f(ushort b) {
    union { unsigned u; float f; } v; v.u = ((unsigned)b) << 16;
    return v.f;
}

// tanh jet: a, a'=1-a^2, a''=-2a·a'
__device__ __forceinline__ void jet(float z, float zt, float zx, float zy,
                                    float zxx, float zyy,
                                    float& s0, float& s1, float& s2,
                                    float& s3, float& s4, float& s5) {
    float e  = __expf(2.0f * z);
    float a  = 1.0f - 2.0f * __builtin_amdgcn_rcpf(e + 1.0f);
    float ap = 1.0f - a * a;
    float am = -2.0f * a * ap;
    s0 = a;
    s1 = ap * zt;
    s2 = ap * zx;
    s3 = ap * zy;
    s4 = ap * zxx + am * zx * zx;
    s5 = ap * zyy + am * zy * zy;
}

// ---- jet LDS: row sp = stream*16 + point (512 B/row), XOR-swizzled slots ----
// slot bits [6:4] ^= (sp ^ (sp>>3)) & 7  -> consecutive-8-lane reads hit 8 slots,
// and store pairs (p, p+8) land in different slots (was 4-way, now <=2-way).
__device__ __forceinline__ int swzoff(int sp, int byteInRow) {
    return (sp << 9) + (byteInRow ^ ((((sp >> 3) ^ sp) & 7) << 4));
}
__device__ __forceinline__ void storeB(char* baseB, int sp, int j0,
                                       ushort a0, ushort a1, ushort a2, ushort a3) {
    *(ushort4*)(baseB + swzoff(sp, j0 * 2)) = make_ushort4(a0, a1, a2, a3);
}

// ============ prep: W1..W3 -> bf16 hi/lo in 32x32x16 A-fragment order ============
// A-frag (mirrors verified 16x16x32): lane 32g+r holds A[row r][k = 8g+jj], jj=0..7.
// A = W^T: row=j (output col), k=input. Frag idx = ((M*16 + kt)*64 + lane), M=j/32.
__global__ __launch_bounds__(256)
void pinn_prep_kernel(const float* __restrict__ W1, const float* __restrict__ W2,
                      const float* __restrict__ W3, ushort* __restrict__ ws) {
    int gid  = blockIdx.x * 256 + threadIdx.x;  // 0..24575
    int l    = gid >> 13;                       // layer 0..2 (8192 threads each)
    int rem  = gid & 8191;
    int M    = rem >> 10;                       // 0..7
    int kt   = (rem >> 6) & 15;                 // 0..15
    int lane = rem & 63;
    const float* W = (l == 0) ? W1 : (l == 1) ? W2 : W3;
    int j  = M * 32 + (lane & 31);
    int k0 = kt * 16 + (lane >> 5) * 8;
    union { ushort u[8]; short8v v; } hi, lo;
    #pragma unroll
    for (int jj = 0; jj < 8; ++jj) {
        float v  = W[(k0 + jj) * 256 + j];      // W[k][j] row-major
        ushort h = f2bf(v);
        hi.u[jj] = h;
        lo.u[jj] = f2bf(v - bf2f(h));
    }
    int off = l * 8192 + (M * 16 + kt) * 64 + lane;
    ((short8v*)ws)[off]         = hi.v;         // hi frags: [0, 24576)
    ((short8v*)ws)[24576 + off] = lo.v;         // lo frags: [24576, 49152)
}

// ============== main: 16 points / block, 256 threads, 4 waves, 32x32x16 ==============
// Wave wv owns j in [wv*64, wv*64+64) = M-tiles {2wv, 2wv+1}.
// B col-tiles (32 cols = 2 streams x 16 pts): hi T=0..2 (streams 2T,2T+1), lo L=0..1.
// C layout: col=lane&31 -> (s_local=col>>4, p=col&15); row=(reg&3)+8*(reg>>2)+4*(lane>>5).
__global__ __launch_bounds__(256, 2)
void pinn_burger2d_kernel(
    const float* __restrict__ t, const float* __restrict__ x, const float* __restrict__ y,
    const float* __restrict__ W0, const float* __restrict__ b0,
    const float* __restrict__ b1, const float* __restrict__ b2, const float* __restrict__ b3,
    const float* __restrict__ W4, const float* __restrict__ b4,
    const ushort* __restrict__ wf, float* __restrict__ out)
{
    __shared__ ushort BhiS[96 * 256];   // 48 KiB: jet hi, rows sp = s*16+p, s=0..5
    __shared__ ushort BloS[64 * 256];   // 32 KiB: jet lo, s=0..3
    char* bhiB = (char*)BhiS;
    char* bloB = (char*)BloS;

    const int tid  = threadIdx.x;
    const int lane = tid & 63;
    const int wv   = tid >> 6;          // wave 0..3
    const int p    = lane & 15;         // point 0..15
    const int col  = lane & 31;         // MFMA B/C column
    const int sl   = (lane >> 4) & 1;   // stream-parity within col-tile
    const int kg   = lane >> 5;         // k-group / row-group
    const int base = blockIdx.x * 16;
    const int gi   = base + p;

    const float tv = t[gi], xv = x[gi], yv = y[gi];

    // ---------------- layer 0: (t,x,y) -> 256 jet, write to LDS ----------------
    {
        const int rg = lane >> 4;       // 0..3
        #pragma unroll
        for (int m = 0; m < 4; ++m) {
            const int jb = wv * 64 + m * 16 + rg * 4;
            float4 w0t = *(const float4*)(W0 + jb);
            float4 w0x = *(const float4*)(W0 + 256 + jb);
            float4 w0y = *(const float4*)(W0 + 512 + jb);
            float4 bb  = *(const float4*)(b0 + jb);
            float wtA[4] = {w0t.x, w0t.y, w0t.z, w0t.w};
            float wxA[4] = {w0x.x, w0x.y, w0x.z, w0x.w};
            float wyA[4] = {w0y.x, w0y.y, w0y.z, w0y.w};
            float bbA[4] = {bb.x, bb.y, bb.z, bb.w};
            ushort h[6][4]; ushort lw[4][4];
            #pragma unroll
            for (int r = 0; r < 4; ++r) {
                float z = tv * wtA[r] + xv * wxA[r] + yv * wyA[r] + bbA[r];
                float s0, s1, s2, s3, s4, s5;
                jet(z, wtA[r], wxA[r], wyA[r], 0.0f, 0.0f, s0, s1, s2, s3, s4, s5);
                float ss[6] = {s0, s1, s2, s3, s4, s5};
                #pragma unroll
                for (int s = 0; s < 6; ++s) {
                    h[s][r] = f2bf(ss[s]);
                    if (s < 4) lw[s][r] = f2bf(ss[s] - bf2f(h[s][r]));
                }
            }
            #pragma unroll
            for (int s = 0; s < 6; ++s)
                storeB(bhiB, s * 16 + p, jb, h[s][0], h[s][1], h[s][2], h[s][3]);
            #pragma unroll
            for (int s = 0; s < 4; ++s)
                storeB(bloB, s * 16 + p, jb, lw[s][0], lw[s][1], lw[s][2], lw[s][3]);
        }
    }
    __syncthreads();

    f32x16 acc[2][3];   // [M-tile m][C col-tile c]; c covers streams {2c, 2c+1}

    for (int li = 0; li < 3; ++li) {
        #pragma unroll
        for (int m = 0; m < 2; ++m)
            #pragma unroll
            for (int c = 0; c < 3; ++c)
                acc[m][c] = (f32x16)(0.0f);

        const short8v* whf = (const short8v*)wf + li * 8192;
        const short8v* wlf = (const short8v*)wf + 24576 + li * 8192;

        #pragma unroll 2
        for (int kt = 0; kt < 16; ++kt) {
            const int bRow = kt * 32 + kg * 16;     // 16 bytes of k per lane
            short8v bh0 = *(const short8v*)(bhiB + swzoff(col,      bRow));
            short8v bh1 = *(const short8v*)(bhiB + swzoff(32 + col, bRow));
            short8v bh2 = *(const short8v*)(bhiB + swzoff(64 + col, bRow));
            short8v bl0 = *(const short8v*)(bloB + swzoff(col,      bRow));
            short8v bl1 = *(const short8v*)(bloB + swzoff(32 + col, bRow));
            const int fa = (wv * 32 + kt) * 64 + lane;   // M = 2wv
            short8v whA = whf[fa];
            short8v wlA = wlf[fa];
            short8v whB = whf[fa + 1024];                // M = 2wv+1
            short8v wlB = wlf[fa + 1024];
            acc[0][0] = __builtin_amdgcn_mfma_f32_32x32x16_bf16(whA, bh0, acc[0][0], 0, 0, 0);
            acc[0][0] = __builtin_amdgcn_mfma_f32_32x32x16_bf16(wlA, bh0, acc[0][0], 0, 0, 0);
            acc[0][0] = __builtin_amdgcn_mfma_f32_32x32x16_bf16(whA, bl0, acc[0][0], 0, 0, 0);
            acc[0][1] = __builtin_amdgcn_mfma_f32_32x32x16_bf16(whA, bh1, acc[0][1], 0, 0, 0);
            acc[0][1] = __builtin_amdgcn_mfma_f32_32x32x16_bf16(wlA, bh1, acc[0][1], 0, 0, 0);
            acc[0][1] = __builtin_amdgcn_mfma_f32_32x32x16_bf16(whA, bl1, acc[0][1], 0, 0, 0);
            acc[0][2] = __builtin_amdgcn_mfma_f32_32x32x16_bf16(whA, bh2, acc[0][2], 0, 0, 0);
            acc[0][2] = __builtin_amdgcn_mfma_f32_32x32x16_bf16(wlA, bh2, acc[0][2], 0, 0, 0);
            acc[1][0] = __builtin_amdgcn_mfma_f32_32x32x16_bf16(whB, bh0, acc[1][0], 0, 0, 0);
            acc[1][0] = __builtin_amdgcn_mfma_f32_32x32x16_bf16(wlB, bh0, acc[1][0], 0, 0, 0);
            acc[1][0] = __builtin_amdgcn_mfma_f32_32x32x16_bf16(whB, bl0, acc[1][0], 0, 0, 0);
            acc[1][1] = __builtin_amdgcn_mfma_f32_32x32x16_bf16(whB, bh1, acc[1][1], 0, 0, 0);
            acc[1][1] = __builtin_amdgcn_mfma_f32_32x32x16_bf16(wlB, bh1, acc[1][1], 0, 0, 0);
            acc[1][1] = __builtin_amdgcn_mfma_f32_32x32x16_bf16(whB, bl1, acc[1][1], 0, 0, 0);
            acc[1][2] = __builtin_amdgcn_mfma_f32_32x32x16_bf16(whB, bh2, acc[1][2], 0, 0, 0);
            acc[1][2] = __builtin_amdgcn_mfma_f32_32x32x16_bf16(wlB, bh2, acc[1][2], 0, 0, 0);
        }
        __syncthreads();   // all waves done reading jet LDS

        if (li < 2) {
            // ---- exchange (lane <-> lane^16) + tanh jet + store next jet ----
            // Thread handles M-tile mh = sl. Own streams {sl,2+sl,4+sl}; partner has rest.
            const float* bL   = (li == 0) ? b1 : b2;
            const int jbase = (wv * 2 + sl) * 32;
            #pragma unroll
            for (int q = 0; q < 4; ++q) {
                const int r0 = 8 * q + 4 * kg;     // row in tile for reg 4q..4q+3
                float4 bb = *(const float4*)(bL + jbase + r0);
                float bbA[4] = {bb.x, bb.y, bb.z, bb.w};
                ushort h[6][4]; ushort lw[4][4];
                #pragma unroll
                for (int i = 0; i < 4; ++i) {
                    const int r = 4 * q + i;
                    float e[3], o[3];    // e = streams {0,2,4}, o = {1,3,5}
                    #pragma unroll
                    for (int c = 0; c < 3; ++c) {
                        float g0 = __shfl_xor(acc[0][c][r], 16, 64);
                        float g1 = __shfl_xor(acc[1][c][r], 16, 64);
                        float ot = sl ? g1 : g0;                       // partner, my tile
                        float my = sl ? acc[1][c][r] : acc[0][c][r];   // mine, my tile
                        e[c] = sl ? ot : my;
                        o[c] = sl ? my : ot;
                    }
                    float s0, s1, s2, s3, s4, s5;
                    jet(e[0] + bbA[i], o[0], e[1], o[1], e[2], o[2], s0, s1, s2, s3, s4, s5);
                    float ss[6] = {s0, s1, s2, s3, s4, s5};
                    #pragma unroll
                    for (int s = 0; s < 6; ++s) {
                        h[s][i] = f2bf(ss[s]);
                        if (s < 4) lw[s][i] = f2bf(ss[s] - bf2f(h[s][i]));
                    }
                }
                const int j0 = jbase + r0;
                #pragma unroll
                for (int s = 0; s < 6; ++s)
                    storeB(bhiB, s * 16 + p, j0, h[s][0], h[s][1], h[s][2], h[s][3]);
                #pragma unroll
                for (int s = 0; s < 4; ++s)
                    storeB(bloB, s * 16 + p, j0, lw[s][0], lw[s][1], lw[s][2], lw[s][3]);
            }
            __syncthreads();
        }
    }

    // ---------------- layer-3 jet (regs) + final 256->1 dot ----------------
    float part[6] = {0, 0, 0, 0, 0, 0};
    {
        const int jbase = (wv * 2 + sl) * 32;
        #pragma unroll
        for (int q = 0; q < 4; ++q) {
            const int r0 = 8 * q + 4 * kg;
            float4 bb = *(const float4*)(b3 + jbase + r0);
            float4 w4 = *(const float4*)(W4 + jbase + r0);
            float bbA[4] = {bb.x, bb.y, bb.z, bb.w};
            float w4A[4] = {w4.x, w4.y, w4.z, w4.w};
            #pragma unroll
            for (int i = 0; i < 4; ++i) {
                const int r = 4 * q + i;
                float e[3], o[3];
                #pragma unroll
                for (int c = 0; c < 3; ++c) {
                    float g0 = __shfl_xor(acc[0][c][r], 16, 64);
                    float g1 = __shfl_xor(acc[1][c][r], 16, 64);
                    float ot = sl ? g1 : g0;
                    float my = sl ? acc[1][c][r] : acc[0][c][r];
                    e[c] = sl ? ot : my;
                    o[c] = sl ? my : ot;
                }
                float s0, s1, s2, s3, s4, s5;
                jet(e[0] + bbA[i], o[0], e[1], o[1], e[2], o[2], s0, s1, s2, s3, s4, s5);
                part[0] += s0 * w4A[i];
                part[1] += s1 * w4A[i];
                part[2] += s2 * w4A[i];
                part[3] += s3 * w4A[i];
                part[4] += s4 * w4A[i];
                part[5] += s5 * w4A[i];
            }
        }
    }
    // reduce over lanes sharing a point: lane^16 (other tile), lane^32 (other rows)
    #pragma unroll
    for (int s = 0; s < 6; ++s) {
        part[s] += __shfl_xor(part[s], 16, 64);
        part[s] += __shfl_xor(part[s], 32, 64);
    }
    float* resf = (float*)BloS;   // overlay; barrier after last kt loop protects
    if (lane < 16) {
        #pragma unroll
        for (int s = 0; s < 6; ++s) resf[(wv * 6 + s) * 16 + p] = part[s];
    }
    __syncthreads();

    if (tid < 16) {
        const int pp = tid;
        const int g  = base + pp;
        float u = b4[0], ut = 0, ux = 0, uy = 0, uxx = 0, uyy = 0;
        #pragma unroll
        for (int w = 0; w < 4; ++w) {
            u   += resf[(w * 6 + 0) * 16 + pp];
            ut  += resf[(w * 6 + 1) * 16 + pp];
            ux  += resf[(w * 6 + 2) * 16 + pp];
            uy  += resf[(w * 6 + 3) * 16 + pp];
            uxx += resf[(w * 6 + 4) * 16 + pp];
            uyy += resf[(w * 6 + 5) * 16 + pp];
        }
        out[g]        = u;
        out[NPTS + g] = ut + u * ux + u * uy - NU_F * (uxx + uyy);
    }
}

extern "C" void kernel_launch(void* const* d_in, const int* in_sizes, int n_in,
                              void* d_out, int out_size, void* d_ws, size_t ws_size,
                              hipStream_t stream) {
    const float* t  = (const float*)d_in[0];
    const float* x  = (const float*)d_in[1];
    const float* y  = (const float*)d_in[2];
    const float* W0 = (const float*)d_in[3];
    const float* b0 = (const float*)d_in[4];
    const float* W1 = (const float*)d_in[5];
    const float* b1 = (const float*)d_in[6];
    const float* W2 = (const float*)d_in[7];
    const float* b2 = (const float*)d_in[8];
    const float* W3 = (const float*)d_in[9];
    const float* b3 = (const float*)d_in[10];
    const float* W4 = (const float*)d_in[11];
    const float* b4 = (const float*)d_in[12];
    float* out = (float*)d_out;

    pinn_prep_kernel<<<96, 256, 0, stream>>>(W1, W2, W3, (ushort*)d_ws);
    pinn_burger2d_kernel<<<NPTS / 16, 256, 0, stream>>>(
        t, x, y, W0, b0, b1, b2, b3, W4, b4, (const ushort*)d_ws, out);
}

// Round 7
// 192.367 us; speedup vs baseline: 1.9254x; 1.9254x over previous
//
#include <hip/hip_runtime.h>
#include <hip/hip_bf16.h>

#define NPTS 65536
#define NU_F 0.0031830988618379067f

typedef __attribute__((ext_vector_type(8)))  _Float16 half8v;  // 8 fp16 (4 VGPRs)
typedef __attribute__((ext_vector_type(16))) float    f32x16;  // 32x32 MFMA C/D

// tanh jet: a, a'=1-a^2, a''=-2a·a'
__device__ __forceinline__ void jet(float z, float zt, float zx, float zy,
                                    float zxx, float zyy,
                                    float& s0, float& s1, float& s2,
                                    float& s3, float& s4, float& s5) {
    float e  = __expf(2.0f * z);
    float a  = 1.0f - 2.0f * __builtin_amdgcn_rcpf(e + 1.0f);
    float ap = 1.0f - a * a;
    float am = -2.0f * a * ap;
    s0 = a;
    s1 = ap * zt;
    s2 = ap * zx;
    s3 = ap * zy;
    s4 = ap * zxx + am * zx * zx;
    s5 = ap * zyy + am * zy * zy;
}

// ---- jet LDS: row sp = stream*16 + point (512 B/row), XOR-swizzled slots ----
// slot bits [6:4] ^= (sp ^ (sp>>3)) & 7
__device__ __forceinline__ int swzoff(int sp, int byteInRow) {
    return (sp << 9) + (byteInRow ^ ((((sp >> 3) ^ sp) & 7) << 4));
}
union h4u { ushort4 u4; _Float16 h[4]; };
__device__ __forceinline__ void storeB(char* baseB, int sp, int j0,
                                       _Float16 a0, _Float16 a1, _Float16 a2, _Float16 a3) {
    h4u v; v.h[0] = a0; v.h[1] = a1; v.h[2] = a2; v.h[3] = a3;
    *(ushort4*)(baseB + swzoff(sp, j0 * 2)) = v.u4;
}

// ============ prep: W1..W3 -> fp16 in 32x32x16 A-fragment order ============
// A-frag: lane 32g+r holds A[row r][k = 8g+jj], jj=0..7. A = W^T (row=j, k=input).
// Frag idx = (M*16 + kt)*64 + lane, M = j/32. (Layout HW-verified in R6.)
__global__ __launch_bounds__(256)
void pinn_prep_kernel(const float* __restrict__ W1, const float* __restrict__ W2,
                      const float* __restrict__ W3, _Float16* __restrict__ ws) {
    int gid  = blockIdx.x * 256 + threadIdx.x;  // 0..24575
    int l    = gid >> 13;                       // layer 0..2 (8192 threads each)
    int rem  = gid & 8191;
    int M    = rem >> 10;                       // 0..7
    int kt   = (rem >> 6) & 15;                 // 0..15
    int lane = rem & 63;
    const float* W = (l == 0) ? W1 : (l == 1) ? W2 : W3;
    int j  = M * 32 + (lane & 31);
    int k0 = kt * 16 + (lane >> 5) * 8;
    union { _Float16 h[8]; half8v v; } hf;
    #pragma unroll
    for (int jj = 0; jj < 8; ++jj)
        hf.h[jj] = (_Float16)W[(k0 + jj) * 256 + j];   // W[k][j] row-major
    ((half8v*)ws)[l * 8192 + (M * 16 + kt) * 64 + lane] = hf.v;
}

// ============== main: 16 points / block, 256 threads, 4 waves, 32x32x16 f16 ==============
// Wave wv owns j in [wv*64, wv*64+64) = M-tiles {2wv, 2wv+1}.
// B col-tiles (32 cols = 2 streams x 16 pts): c=0..2 covers streams {2c, 2c+1}.
// C layout: col=lane&31 -> (s_local=col>>4, p=col&15); row=(reg&3)+8*(reg>>2)+4*(lane>>5).
// launch_bounds(256,3): 3 waves/EU min -> VGPR budget ~170 (demand ~100, no spills);
// LDS 48 KiB -> 3 blocks/CU.
__global__ __launch_bounds__(256, 3)
void pinn_burger2d_kernel(
    const float* __restrict__ t, const float* __restrict__ x, const float* __restrict__ y,
    const float* __restrict__ W0, const float* __restrict__ b0,
    const float* __restrict__ b1, const float* __restrict__ b2, const float* __restrict__ b3,
    const float* __restrict__ W4, const float* __restrict__ b4,
    const _Float16* __restrict__ wf, float* __restrict__ out)
{
    __shared__ _Float16 BjS[96 * 256];   // 48 KiB: jet fp16, rows sp = s*16+p, s=0..5
    char* bjB = (char*)BjS;

    const int tid  = threadIdx.x;
    const int lane = tid & 63;
    const int wv   = tid >> 6;          // wave 0..3
    const int p    = lane & 15;         // point 0..15
    const int col  = lane & 31;         // MFMA B/C column
    const int sl   = (lane >> 4) & 1;   // stream-parity within col-tile
    const int kg   = lane >> 5;         // k-group / row-group
    const int base = blockIdx.x * 16;
    const int gi   = base + p;

    const float tv = t[gi], xv = x[gi], yv = y[gi];

    // ---------------- layer 0: (t,x,y) -> 256 jet, write to LDS ----------------
    {
        const int rg = lane >> 4;       // 0..3
        #pragma unroll
        for (int m = 0; m < 4; ++m) {
            const int jb = wv * 64 + m * 16 + rg * 4;
            float4 w0t = *(const float4*)(W0 + jb);
            float4 w0x = *(const float4*)(W0 + 256 + jb);
            float4 w0y = *(const float4*)(W0 + 512 + jb);
            float4 bb  = *(const float4*)(b0 + jb);
            float wtA[4] = {w0t.x, w0t.y, w0t.z, w0t.w};
            float wxA[4] = {w0x.x, w0x.y, w0x.z, w0x.w};
            float wyA[4] = {w0y.x, w0y.y, w0y.z, w0y.w};
            float bbA[4] = {bb.x, bb.y, bb.z, bb.w};
            _Float16 h[6][4];
            #pragma unroll
            for (int r = 0; r < 4; ++r) {
                float z = tv * wtA[r] + xv * wxA[r] + yv * wyA[r] + bbA[r];
                float s0, s1, s2, s3, s4, s5;
                jet(z, wtA[r], wxA[r], wyA[r], 0.0f, 0.0f, s0, s1, s2, s3, s4, s5);
                h[0][r] = (_Float16)s0; h[1][r] = (_Float16)s1; h[2][r] = (_Float16)s2;
                h[3][r] = (_Float16)s3; h[4][r] = (_Float16)s4; h[5][r] = (_Float16)s5;
            }
            #pragma unroll
            for (int s = 0; s < 6; ++s)
                storeB(bjB, s * 16 + p, jb, h[s][0], h[s][1], h[s][2], h[s][3]);
        }
    }
    __syncthreads();

    f32x16 acc[2][3];   // [M-tile m][col-tile c]; c covers streams {2c, 2c+1}

    for (int li = 0; li < 3; ++li) {
        #pragma unroll
        for (int m = 0; m < 2; ++m)
            #pragma unroll
            for (int c = 0; c < 3; ++c)
                acc[m][c] = (f32x16)(0.0f);

        const half8v* whf = (const half8v*)wf + li * 8192;

        #pragma unroll 4
        for (int kt = 0; kt < 16; ++kt) {
            const int bRow = kt * 32 + kg * 16;     // 16 bytes of k per lane
            half8v bh0 = *(const half8v*)(bjB + swzoff(col,      bRow));
            half8v bh1 = *(const half8v*)(bjB + swzoff(32 + col, bRow));
            half8v bh2 = *(const half8v*)(bjB + swzoff(64 + col, bRow));
            const int fa = (wv * 32 + kt) * 64 + lane;   // M = 2wv
            half8v whA = whf[fa];
            half8v whB = whf[fa + 1024];                 // M = 2wv+1
            acc[0][0] = __builtin_amdgcn_mfma_f32_32x32x16_f16(whA, bh0, acc[0][0], 0, 0, 0);
            acc[0][1] = __builtin_amdgcn_mfma_f32_32x32x16_f16(whA, bh1, acc[0][1], 0, 0, 0);
            acc[0][2] = __builtin_amdgcn_mfma_f32_32x32x16_f16(whA, bh2, acc[0][2], 0, 0, 0);
            acc[1][0] = __builtin_amdgcn_mfma_f32_32x32x16_f16(whB, bh0, acc[1][0], 0, 0, 0);
            acc[1][1] = __builtin_amdgcn_mfma_f32_32x32x16_f16(whB, bh1, acc[1][1], 0, 0, 0);
            acc[1][2] = __builtin_amdgcn_mfma_f32_32x32x16_f16(whB, bh2, acc[1][2], 0, 0, 0);
        }
        __syncthreads();   // all waves done reading jet LDS

        if (li < 2) {
            // ---- exchange (lane <-> lane^16) + tanh jet + store next jet ----
            const float* bL = (li == 0) ? b1 : b2;
            const int jbase = (wv * 2 + sl) * 32;
            #pragma unroll
            for (int q = 0; q < 4; ++q) {
                const int r0 = 8 * q + 4 * kg;     // row in tile for reg 4q..4q+3
                float4 bb = *(const float4*)(bL + jbase + r0);
                float bbA[4] = {bb.x, bb.y, bb.z, bb.w};
                _Float16 h[6][4];
                #pragma unroll
                for (int i = 0; i < 4; ++i) {
                    const int r = 4 * q + i;
                    float e[3], o[3];    // e = streams {0,2,4}, o = {1,3,5}
                    #pragma unroll
                    for (int c = 0; c < 3; ++c) {
                        float g0 = __shfl_xor(acc[0][c][r], 16, 64);
                        float g1 = __shfl_xor(acc[1][c][r], 16, 64);
                        float ot = sl ? g1 : g0;                       // partner, my tile
                        float my = sl ? acc[1][c][r] : acc[0][c][r];   // mine, my tile
                        e[c] = sl ? ot : my;
                        o[c] = sl ? my : ot;
                    }
                    float s0, s1, s2, s3, s4, s5;
                    jet(e[0] + bbA[i], o[0], e[1], o[1], e[2], o[2], s0, s1, s2, s3, s4, s5);
                    h[0][i] = (_Float16)s0; h[1][i] = (_Float16)s1; h[2][i] = (_Float16)s2;
                    h[3][i] = (_Float16)s3; h[4][i] = (_Float16)s4; h[5][i] = (_Float16)s5;
                }
                const int j0 = jbase + r0;
                #pragma unroll
                for (int s = 0; s < 6; ++s)
                    storeB(bjB, s * 16 + p, j0, h[s][0], h[s][1], h[s][2], h[s][3]);
            }
            __syncthreads();
        }
    }

    // ---------------- layer-3 jet (regs) + final 256->1 dot ----------------
    float part[6] = {0, 0, 0, 0, 0, 0};
    {
        const int jbase = (wv * 2 + sl) * 32;
        #pragma unroll
        for (int q = 0; q < 4; ++q) {
            const int r0 = 8 * q + 4 * kg;
            float4 bb = *(const float4*)(b3 + jbase + r0);
            float4 w4 = *(const float4*)(W4 + jbase + r0);
            float bbA[4] = {bb.x, bb.y, bb.z, bb.w};
            float w4A[4] = {w4.x, w4.y, w4.z, w4.w};
            #pragma unroll
            for (int i = 0; i < 4; ++i) {
                const int r = 4 * q + i;
                float e[3], o[3];
                #pragma unroll
                for (int c = 0; c < 3; ++c) {
                    float g0 = __shfl_xor(acc[0][c][r], 16, 64);
                    float g1 = __shfl_xor(acc[1][c][r], 16, 64);
                    float ot = sl ? g1 : g0;
                    float my = sl ? acc[1][c][r] : acc[0][c][r];
                    e[c] = sl ? ot : my;
                    o[c] = sl ? my : ot;
                }
                float s0, s1, s2, s3, s4, s5;
                jet(e[0] + bbA[i], o[0], e[1], o[1], e[2], o[2], s0, s1, s2, s3, s4, s5);
                part[0] += s0 * w4A[i];
                part[1] += s1 * w4A[i];
                part[2] += s2 * w4A[i];
                part[3] += s3 * w4A[i];
                part[4] += s4 * w4A[i];
                part[5] += s5 * w4A[i];
            }
        }
    }
    // reduce over lanes sharing a point: lane^16 (other tile), lane^32 (other rows)
    #pragma unroll
    for (int s = 0; s < 6; ++s) {
        part[s] += __shfl_xor(part[s], 16, 64);
        part[s] += __shfl_xor(part[s], 32, 64);
    }
    float* resf = (float*)BjS;   // overlay; barrier after last kt loop protects
    if (lane < 16) {
        #pragma unroll
        for (int s = 0; s < 6; ++s) resf[(wv * 6 + s) * 16 + p] = part[s];
    }
    __syncthreads();

    if (tid < 16) {
        const int pp = tid;
        const int g  = base + pp;
        float u = b4[0], ut = 0, ux = 0, uy = 0, uxx = 0, uyy = 0;
        #pragma unroll
        for (int w = 0; w < 4; ++w) {
            u   += resf[(w * 6 + 0) * 16 + pp];
            ut  += resf[(w * 6 + 1) * 16 + pp];
            ux  += resf[(w * 6 + 2) * 16 + pp];
            uy  += resf[(w * 6 + 3) * 16 + pp];
            uxx += resf[(w * 6 + 4) * 16 + pp];
            uyy += resf[(w * 6 + 5) * 16 + pp];
        }
        out[g]        = u;
        out[NPTS + g] = ut + u * ux + u * uy - NU_F * (uxx + uyy);
    }
}

extern "C" void kernel_launch(void* const* d_in, const int* in_sizes, int n_in,
                              void* d_out, int out_size, void* d_ws, size_t ws_size,
                              hipStream_t stream) {
    const float* t  = (const float*)d_in[0];
    const float* x  = (const float*)d_in[1];
    const float* y  = (const float*)d_in[2];
    const float* W0 = (const float*)d_in[3];
    const float* b0 = (const float*)d_in[4];
    const float* W1 = (const float*)d_in[5];
    const float* b1 = (const float*)d_in[6];
    const float* W2 = (const float*)d_in[7];
    const float* b2 = (const float*)d_in[8];
    const float* W3 = (const float*)d_in[9];
    const float* b3 = (const float*)d_in[10];
    const float* W4 = (const float*)d_in[11];
    const float* b4 = (const float*)d_in[12];
    float* out = (float*)d_out;

    pinn_prep_kernel<<<96, 256, 0, stream>>>(W1, W2, W3, (_Float16*)d_ws);
    pinn_burger2d_kernel<<<NPTS / 16, 256, 0, stream>>>(
        t, x, y, W0, b0, b1, b2, b3, W4, b4, (const _Float16*)d_ws, out);
}

// Round 8
// 136.381 us; speedup vs baseline: 2.7159x; 1.4105x over previous
//
#include <hip/hip_runtime.h>

#define NPTS 65536
#define NU_F 0.0031830988618379067f

typedef __attribute__((ext_vector_type(8)))  _Float16 half8v;  // 8 fp16 (4 VGPRs)
typedef __attribute__((ext_vector_type(16))) float    f32x16;  // 32x32 MFMA C/D

// 5-stream tanh jet: value, d/dt, d/dx, d/dy, laplacian (uxx+uyy merged — linear
// through W; tanh update needs only zx, zy individually, which streams 2,3 carry).
__device__ __forceinline__ void jet5(float z, float zt, float zx, float zy, float zl,
                                     float& s0, float& s1, float& s2, float& s3, float& s4) {
    float e  = __expf(2.0f * z);
    float a  = 1.0f - 2.0f * __builtin_amdgcn_rcpf(e + 1.0f);
    float ap = 1.0f - a * a;
    float am = -2.0f * a * ap;
    s0 = a;
    s1 = ap * zt;
    s2 = ap * zx;
    s3 = ap * zy;
    s4 = ap * zl + am * (zx * zx + zy * zy);
}

// ---- jet LDS: row sp = stream*32 + point (512 B/row), slot bits [8:4] ^= sp&31 ----
__device__ __forceinline__ int swzoff(int sp, int byteInRow) {
    return (sp << 9) + (byteInRow ^ ((sp & 31) << 4));
}
union h4u { ushort4 u4; _Float16 h[4]; };
__device__ __forceinline__ void storeJ(char* baseB, int sp, int j0,
                                       _Float16 a0, _Float16 a1, _Float16 a2, _Float16 a3) {
    h4u v; v.h[0] = a0; v.h[1] = a1; v.h[2] = a2; v.h[3] = a3;
    *(ushort4*)(baseB + swzoff(sp, j0 * 2)) = v.u4;
}

// ============ prep: W1..W3 -> fp16 in 32x32x16 A-fragment order (HW-verified R6/R7) ============
// A-frag: lane 32g+r holds A[row r][k = 8g+jj], jj=0..7. A = W^T (row=j, k=input).
// Frag idx = (M*16 + kt)*64 + lane, M = j/32.
__global__ __launch_bounds__(256)
void pinn_prep_kernel(const float* __restrict__ W1, const float* __restrict__ W2,
                      const float* __restrict__ W3, _Float16* __restrict__ ws) {
    int gid  = blockIdx.x * 256 + threadIdx.x;  // 0..24575
    int l    = gid >> 13;                       // layer 0..2
    int rem  = gid & 8191;
    int M    = rem >> 10;                       // 0..7
    int kt   = (rem >> 6) & 15;                 // 0..15
    int lane = rem & 63;
    const float* W = (l == 0) ? W1 : (l == 1) ? W2 : W3;
    int j  = M * 32 + (lane & 31);
    int k0 = kt * 16 + (lane >> 5) * 8;
    union { _Float16 h[8]; half8v v; } hf;
    #pragma unroll
    for (int jj = 0; jj < 8; ++jj)
        hf.h[jj] = (_Float16)W[(k0 + jj) * 256 + j];   // W[k][j] row-major
    ((half8v*)ws)[l * 8192 + (M * 16 + kt) * 64 + lane] = hf.v;
}

// ============== main: 32 points / block, 256 threads, 4 waves, 5 streams ==============
// Wave wv owns j in [wv*64, wv*64+64) = M-tiles {2wv, 2wv+1}. B col-tile c = stream c
// (32 cols = 32 points). C layout: col=lane&31=point; row=(reg&3)+8*(reg>>2)+4*(lane>>5).
// All 5 streams of a (point,j) are lane-local -> no cross-lane exchange.
__global__ __launch_bounds__(256, 2)
void pinn_burger2d_kernel(
    const float* __restrict__ t, const float* __restrict__ x, const float* __restrict__ y,
    const float* __restrict__ W0, const float* __restrict__ b0,
    const float* __restrict__ b1, const float* __restrict__ b2, const float* __restrict__ b3,
    const float* __restrict__ W4, const float* __restrict__ b4,
    const _Float16* __restrict__ wf, float* __restrict__ out)
{
    __shared__ _Float16 BjS[5 * 32 * 256];   // 80 KiB: rows sp = s*32 + p
    char* bjB = (char*)BjS;

    const int tid  = threadIdx.x;
    const int lane = tid & 63;
    const int wv   = tid >> 6;          // wave 0..3
    const int p    = lane & 31;         // point 0..31 (MFMA B/C column)
    const int kg   = lane >> 5;         // k-group / row-group (0/1)
    const int base = blockIdx.x * 32;
    const int gi   = base + p;

    const float tv = t[gi], xv = x[gi], yv = y[gi];

    // ---------------- layer 0: (t,x,y) -> 256-wide 5-stream jet, to LDS ----------------
    #pragma unroll
    for (int m = 0; m < 2; ++m) {
        #pragma unroll
        for (int q = 0; q < 4; ++q) {
            const int j0 = wv * 64 + m * 32 + kg * 16 + q * 4;
            float4 w0t = *(const float4*)(W0 + j0);
            float4 w0x = *(const float4*)(W0 + 256 + j0);
            float4 w0y = *(const float4*)(W0 + 512 + j0);
            float4 bb  = *(const float4*)(b0 + j0);
            float wtA[4] = {w0t.x, w0t.y, w0t.z, w0t.w};
            float wxA[4] = {w0x.x, w0x.y, w0x.z, w0x.w};
            float wyA[4] = {w0y.x, w0y.y, w0y.z, w0y.w};
            float bbA[4] = {bb.x, bb.y, bb.z, bb.w};
            _Float16 h[5][4];
            #pragma unroll
            for (int i = 0; i < 4; ++i) {
                float z = tv * wtA[i] + xv * wxA[i] + yv * wyA[i] + bbA[i];
                float s0, s1, s2, s3, s4;
                jet5(z, wtA[i], wxA[i], wyA[i], 0.0f, s0, s1, s2, s3, s4);
                h[0][i] = (_Float16)s0; h[1][i] = (_Float16)s1; h[2][i] = (_Float16)s2;
                h[3][i] = (_Float16)s3; h[4][i] = (_Float16)s4;
            }
            #pragma unroll
            for (int s = 0; s < 5; ++s)
                storeJ(bjB, s * 32 + p, j0, h[s][0], h[s][1], h[s][2], h[s][3]);
        }
    }
    __syncthreads();

    f32x16 acc[2][5];   // [M-tile m][stream c]

    for (int li = 0; li < 3; ++li) {
        #pragma unroll
        for (int m = 0; m < 2; ++m)
            #pragma unroll
            for (int c = 0; c < 5; ++c)
                acc[m][c] = (f32x16)(0.0f);

        const half8v* whf = (const half8v*)wf + li * 8192;

        #pragma unroll 4
        for (int kt = 0; kt < 16; ++kt) {
            const int bRow = kt * 32 + kg * 16;     // 16 bytes of k per lane
            half8v bv0 = *(const half8v*)(bjB + swzoff(       p, bRow));
            half8v bv1 = *(const half8v*)(bjB + swzoff( 32 + p, bRow));
            half8v bv2 = *(const half8v*)(bjB + swzoff( 64 + p, bRow));
            half8v bv3 = *(const half8v*)(bjB + swzoff( 96 + p, bRow));
            half8v bv4 = *(const half8v*)(bjB + swzoff(128 + p, bRow));
            const int fa = (wv * 32 + kt) * 64 + lane;   // M = 2wv
            half8v whA = whf[fa];
            half8v whB = whf[fa + 1024];                 // M = 2wv+1
            acc[0][0] = __builtin_amdgcn_mfma_f32_32x32x16_f16(whA, bv0, acc[0][0], 0, 0, 0);
            acc[0][1] = __builtin_amdgcn_mfma_f32_32x32x16_f16(whA, bv1, acc[0][1], 0, 0, 0);
            acc[0][2] = __builtin_amdgcn_mfma_f32_32x32x16_f16(whA, bv2, acc[0][2], 0, 0, 0);
            acc[0][3] = __builtin_amdgcn_mfma_f32_32x32x16_f16(whA, bv3, acc[0][3], 0, 0, 0);
            acc[0][4] = __builtin_amdgcn_mfma_f32_32x32x16_f16(whA, bv4, acc[0][4], 0, 0, 0);
            acc[1][0] = __builtin_amdgcn_mfma_f32_32x32x16_f16(whB, bv0, acc[1][0], 0, 0, 0);
            acc[1][1] = __builtin_amdgcn_mfma_f32_32x32x16_f16(whB, bv1, acc[1][1], 0, 0, 0);
            acc[1][2] = __builtin_amdgcn_mfma_f32_32x32x16_f16(whB, bv2, acc[1][2], 0, 0, 0);
            acc[1][3] = __builtin_amdgcn_mfma_f32_32x32x16_f16(whB, bv3, acc[1][3], 0, 0, 0);
            acc[1][4] = __builtin_amdgcn_mfma_f32_32x32x16_f16(whB, bv4, acc[1][4], 0, 0, 0);
        }
        __syncthreads();   // all waves done reading jet LDS

        if (li < 2) {
            // ---- lane-local tanh jet + store next jet (no shuffles) ----
            const float* bL = (li == 0) ? b1 : b2;
            #pragma unroll
            for (int m = 0; m < 2; ++m) {
                const int jt = (wv * 2 + m) * 32;
                #pragma unroll
                for (int q = 0; q < 4; ++q) {
                    const int j0 = jt + 8 * q + 4 * kg;    // rows for regs 4q..4q+3
                    float4 bb = *(const float4*)(bL + j0);
                    float bbA[4] = {bb.x, bb.y, bb.z, bb.w};
                    _Float16 h[5][4];
                    #pragma unroll
                    for (int i = 0; i < 4; ++i) {
                        const int r = 4 * q + i;
                        float s0, s1, s2, s3, s4;
                        jet5(acc[m][0][r] + bbA[i], acc[m][1][r], acc[m][2][r],
                             acc[m][3][r], acc[m][4][r], s0, s1, s2, s3, s4);
                        h[0][i] = (_Float16)s0; h[1][i] = (_Float16)s1; h[2][i] = (_Float16)s2;
                        h[3][i] = (_Float16)s3; h[4][i] = (_Float16)s4;
                    }
                    #pragma unroll
                    for (int s = 0; s < 5; ++s)
                        storeJ(bjB, s * 32 + p, j0, h[s][0], h[s][1], h[s][2], h[s][3]);
                }
            }
            __syncthreads();
        }
    }

    // ---------------- layer-3 jet (lane-local) + final 256->1 dot ----------------
    float part[5] = {0, 0, 0, 0, 0};
    #pragma unroll
    for (int m = 0; m < 2; ++m) {
        const int jt = (wv * 2 + m) * 32;
        #pragma unroll
        for (int q = 0; q < 4; ++q) {
            const int j0 = jt + 8 * q + 4 * kg;
            float4 bb = *(const float4*)(b3 + j0);
            float4 w4 = *(const float4*)(W4 + j0);
            float bbA[4] = {bb.x, bb.y, bb.z, bb.w};
            float w4A[4] = {w4.x, w4.y, w4.z, w4.w};
            #pragma unroll
            for (int i = 0; i < 4; ++i) {
                const int r = 4 * q + i;
                float s0, s1, s2, s3, s4;
                jet5(acc[m][0][r] + bbA[i], acc[m][1][r], acc[m][2][r],
                     acc[m][3][r], acc[m][4][r], s0, s1, s2, s3, s4);
                part[0] += s0 * w4A[i];
                part[1] += s1 * w4A[i];
                part[2] += s2 * w4A[i];
                part[3] += s3 * w4A[i];
                part[4] += s4 * w4A[i];
            }
        }
    }
    // lanes l and l^32 share a point (different row-halves)
    #pragma unroll
    for (int s = 0; s < 5; ++s) part[s] += __shfl_xor(part[s], 32, 64);

    float* resf = (float*)BjS;   // overlay; sync after last kt loop protects
    if (lane < 32) {
        #pragma unroll
        for (int s = 0; s < 5; ++s) resf[(wv * 5 + s) * 32 + p] = part[s];
    }
    __syncthreads();

    if (tid < 32) {
        const int pp = tid;
        const int g  = base + pp;
        float u = b4[0], ut = 0, ux = 0, uy = 0, lap = 0;
        #pragma unroll
        for (int w = 0; w < 4; ++w) {
            u   += resf[(w * 5 + 0) * 32 + pp];
            ut  += resf[(w * 5 + 1) * 32 + pp];
            ux  += resf[(w * 5 + 2) * 32 + pp];
            uy  += resf[(w * 5 + 3) * 32 + pp];
            lap += resf[(w * 5 + 4) * 32 + pp];
        }
        out[g]        = u;
        out[NPTS + g] = ut + u * ux + u * uy - NU_F * lap;
    }
}

extern "C" void kernel_launch(void* const* d_in, const int* in_sizes, int n_in,
                              void* d_out, int out_size, void* d_ws, size_t ws_size,
                              hipStream_t stream) {
    const float* t  = (const float*)d_in[0];
    const float* x  = (const float*)d_in[1];
    const float* y  = (const float*)d_in[2];
    const float* W0 = (const float*)d_in[3];
    const float* b0 = (const float*)d_in[4];
    const float* W1 = (const float*)d_in[5];
    const float* b1 = (const float*)d_in[6];
    const float* W2 = (const float*)d_in[7];
    const float* b2 = (const float*)d_in[8];
    const float* W3 = (const float*)d_in[9];
    const float* b3 = (const float*)d_in[10];
    const float* W4 = (const float*)d_in[11];
    const float* b4 = (const float*)d_in[12];
    float* out = (float*)d_out;

    pinn_prep_kernel<<<96, 256, 0, stream>>>(W1, W2, W3, (_Float16*)d_ws);
    pinn_burger2d_kernel<<<NPTS / 32, 256, 0, stream>>>(
        t, x, y, W0, b0, b1, b2, b3, W4, b4, (const _Float16*)d_ws, out);
}